// Round 1
// baseline (185.118 us; speedup 1.0000x reference)
//
#include <hip/hip_runtime.h>
#include <math.h>

// Problem geometry (fixed by the reference's setup_inputs)
#define NAUX 32
#define NB   64
#define NF   80
#define NT   640
#define PERB (NF * NT)          // 51200 elements per batch
#define NTOT (NB * PERB)        // 3276800 elements per channel
#define NWORDS (NTOT / 32)      // 102400 mask words per channel
#define THR  20.0f

// ---------------------------------------------------------------------------
// Kernel A: strain peak mask, bit-packed, + per-batch c1 counts.
// Peak test is over the FULL flattened [B,F,T] channel (crosses batch
// boundaries); only channel-flat indices 0 and NTOT-1 are excluded.
// clip(min=0) is a no-op given the >=20 requirement (see analysis).
// ---------------------------------------------------------------------------
__global__ __launch_bounds__(256) void strain_mask_kernel(
    const float* __restrict__ qs,
    unsigned int* __restrict__ maskw,
    unsigned int* __restrict__ c1w)
{
    const int b   = blockIdx.x;
    const int tid = threadIdx.x;
    unsigned int cnt = 0;

    #pragma unroll 4
    for (int it = 0; it < PERB / 256; ++it) {
        const int e = b * PERB + it * 256 + tid;   // channel-flat index
        const float x  = qs[e];
        const float xm = (e == 0)        ? INFINITY : qs[e - 1];
        const float xp = (e == NTOT - 1) ? INFINITY : qs[e + 1];
        const bool pred = (x >= THR) && (x > xm) && (x > xp);

        // 64 consecutive elements per wave -> two packed words
        const unsigned long long bal = __ballot(pred ? 1 : 0);
        if ((tid & 63) == 0) {
            const int w = e >> 5;                  // e is a multiple of 64 here
            maskw[w]     = (unsigned int)(bal & 0xffffffffull);
            maskw[w + 1] = (unsigned int)(bal >> 32);
        }
        cnt += pred ? 1u : 0u;
    }

    __shared__ unsigned int s[256];
    s[tid] = cnt;
    __syncthreads();
    for (int off = 128; off > 0; off >>= 1) {
        if (tid < off) s[tid] += s[tid + off];
        __syncthreads();
    }
    if (tid == 0) c1w[b] = s[0];
}

// ---------------------------------------------------------------------------
// Kernel B: one block per (aux channel n, batch b). float4 sweep of the
// batch's 51200 elements; aux peak predicate AND strain mask bits; block
// reduction; thread 0 computes jaccard + ratio with the reference's
// zero_union / nan_to_num rules.
// ---------------------------------------------------------------------------
__global__ __launch_bounds__(256) void aux_stats_kernel(
    const float* __restrict__ qa,
    const unsigned int* __restrict__ maskw,
    const unsigned int* __restrict__ c1w,
    float* __restrict__ out)
{
    const int n   = blockIdx.x >> 6;   // / NB
    const int b   = blockIdx.x & 63;   // % NB
    const int tid = threadIdx.x;
    const float* __restrict__ pn = qa + (size_t)n * NTOT;

    unsigned int inter = 0, c2 = 0;

    #pragma unroll 2
    for (int it = 0; it < PERB / (256 * 4); ++it) {       // 50 iterations
        const int e = b * PERB + (it * 256 + tid) * 4;    // channel-flat, %4==0
        const float4 v = *reinterpret_cast<const float4*>(pn + e);
        const float xm = (e == 0)        ? INFINITY : pn[e - 1];
        const float xp = (e == NTOT - 4) ? INFINITY : pn[e + 4];

        unsigned int pb = 0;
        pb |= ((v.x >= THR) && (v.x > xm)  && (v.x > v.y)) ? 1u : 0u;
        pb |= ((v.y >= THR) && (v.y > v.x) && (v.y > v.z)) ? 2u : 0u;
        pb |= ((v.z >= THR) && (v.z > v.y) && (v.z > v.w)) ? 4u : 0u;
        pb |= ((v.w >= THR) && (v.w > v.z) && (v.w > xp))  ? 8u : 0u;

        const unsigned int sm = (maskw[e >> 5] >> (e & 31)) & 0xFu;
        c2    += __popc(pb);
        inter += __popc(pb & sm);
    }

    __shared__ unsigned int si[256];
    __shared__ unsigned int sc[256];
    si[tid] = inter; sc[tid] = c2;
    __syncthreads();
    for (int off = 128; off > 0; off >>= 1) {
        if (tid < off) { si[tid] += si[tid + off]; sc[tid] += sc[tid + off]; }
        __syncthreads();
    }

    if (tid == 0) {
        const float fi = (float)si[0];
        const float f1 = (float)c1w[b];
        const float f2 = (float)sc[0];
        const float un = f1 + f2 - fi;
        float jac, ratio;
        if (fi == 0.0f && un == 0.0f) {        // zero_union -> 1.0, 1.0
            jac = 1.0f; ratio = 1.0f;
        } else {
            jac   = fi / un;                    // un >= max(c1,c2) > 0 here
            ratio = (f1 > 0.0f) ? (fi / f1) : 0.0f;   // 0/0 -> nan_to_num -> 0
        }
        out[n * NB + b]             = jac;     // iou.reshape(-1)
        out[NAUX * NB + n * NB + b] = ratio;   // corr.reshape(-1)
    }
}

extern "C" void kernel_launch(void* const* d_in, const int* in_sizes, int n_in,
                              void* d_out, int out_size, void* d_ws, size_t ws_size,
                              hipStream_t stream) {
    const float* qs = (const float*)d_in[0];   // [64, 80, 640]
    const float* qa = (const float*)d_in[1];   // [32, 64, 80, 640]
    float* out = (float*)d_out;                // [4096] = iou ++ corr

    unsigned int* maskw = (unsigned int*)d_ws;       // 102400 words = 400 KB
    unsigned int* c1w   = maskw + NWORDS;            // 64 words

    strain_mask_kernel<<<NB, 256, 0, stream>>>(qs, maskw, c1w);
    aux_stats_kernel<<<NAUX * NB, 256, 0, stream>>>(qa, maskw, c1w, out);
}

// Round 2
// 110.359 us; speedup vs baseline: 1.6774x; 1.6774x over previous
//
#include <hip/hip_runtime.h>
#include <math.h>

// Problem geometry (fixed by the reference's setup_inputs)
#define NAUX 32
#define NB   64
#define NF   80
#define NT   640
#define PERB (NF * NT)          // 51200 elements per batch
#define NTOT (NB * PERB)        // 3276800 elements per channel
#define NGRP (NTOT / 4)         // 819200 4-element groups -> mask bytes
#define THR  20.0f

// ---------------------------------------------------------------------------
// Strict-local-max predicate over the FULL flattened [B,F,T] channel (peaks
// cross batch boundaries; only channel-flat 0 and NTOT-1 excluded).
// clip(min=0) is a no-op given the >=20 requirement.
//
// Mask layout (producer+consumer agree; element order): byte g holds the
// 4-bit predicate nibble for elements 4g..4g+3.
// ---------------------------------------------------------------------------

// Kernel A: 128 blocks = 2 per batch. float4 loads; neighbor exchange via
// wave shuffles (DS pipe) instead of lane-strided scalar gathers (L1 pipe).
__global__ __launch_bounds__(256) void strain_mask_kernel(
    const float* __restrict__ qs,
    unsigned char* __restrict__ maskb,
    unsigned int* __restrict__ c1part)
{
    const int b    = blockIdx.x >> 1;
    const int half = blockIdx.x & 1;
    const int tid  = threadIdx.x;
    const int lane = tid & 63;
    const int base0 = b * PERB + half * (PERB / 2);
    unsigned int cnt = 0;

    for (int it = 0; it < (PERB / 2) / (256 * 4); ++it) {   // 25 iterations
        const int e = base0 + (it * 256 + tid) * 4;         // channel-flat, %4==0
        const float4 v = *reinterpret_cast<const float4*>(qs + e);
        float xm = __shfl_up(v.w, 1);
        float xp = __shfl_down(v.x, 1);
        if (lane == 0)  xm = (e == 0)        ? INFINITY : qs[e - 1];
        if (lane == 63) xp = (e == NTOT - 4) ? INFINITY : qs[e + 4];

        unsigned int pb = 0;
        pb |= ((v.x >= THR) && (v.x > xm)  && (v.x > v.y)) ? 1u : 0u;
        pb |= ((v.y >= THR) && (v.y > v.x) && (v.y > v.z)) ? 2u : 0u;
        pb |= ((v.z >= THR) && (v.z > v.y) && (v.z > v.w)) ? 4u : 0u;
        pb |= ((v.w >= THR) && (v.w > v.z) && (v.w > xp))  ? 8u : 0u;

        maskb[e >> 2] = (unsigned char)pb;                  // coalesced bytes
        cnt += __popc(pb);
    }

    __shared__ unsigned int s[256];
    s[tid] = cnt;
    __syncthreads();
    for (int off = 128; off > 0; off >>= 1) {
        if (tid < off) s[tid] += s[tid + off];
        __syncthreads();
    }
    if (tid == 0) c1part[blockIdx.x] = s[0];
}

// Kernel B: one block per (aux channel n, batch b). Same shuffle scheme;
// mask consumed as coalesced bytes; block reduce; thread 0 writes outputs.
__global__ __launch_bounds__(256) void aux_stats_kernel(
    const float* __restrict__ qa,
    const unsigned char* __restrict__ maskb,
    const unsigned int* __restrict__ c1part,
    float* __restrict__ out)
{
    const int n    = blockIdx.x >> 6;   // / NB
    const int b    = blockIdx.x & 63;   // % NB
    const int tid  = threadIdx.x;
    const int lane = tid & 63;
    const float* __restrict__ pn = qa + (size_t)n * NTOT;

    unsigned int inter = 0, c2 = 0;

    for (int it = 0; it < PERB / (256 * 4); ++it) {         // 50 iterations
        const int e = b * PERB + (it * 256 + tid) * 4;      // channel-flat, %4==0
        const float4 v = *reinterpret_cast<const float4*>(pn + e);
        float xm = __shfl_up(v.w, 1);
        float xp = __shfl_down(v.x, 1);
        if (lane == 0)  xm = (e == 0)        ? INFINITY : pn[e - 1];
        if (lane == 63) xp = (e == NTOT - 4) ? INFINITY : pn[e + 4];

        unsigned int pb = 0;
        pb |= ((v.x >= THR) && (v.x > xm)  && (v.x > v.y)) ? 1u : 0u;
        pb |= ((v.y >= THR) && (v.y > v.x) && (v.y > v.z)) ? 2u : 0u;
        pb |= ((v.z >= THR) && (v.z > v.y) && (v.z > v.w)) ? 4u : 0u;
        pb |= ((v.w >= THR) && (v.w > v.z) && (v.w > xp))  ? 8u : 0u;

        const unsigned int sm = maskb[e >> 2];              // coalesced bytes
        c2    += __popc(pb);
        inter += __popc(pb & sm);
    }

    __shared__ unsigned int si[256];
    __shared__ unsigned int sc[256];
    si[tid] = inter; sc[tid] = c2;
    __syncthreads();
    for (int off = 128; off > 0; off >>= 1) {
        if (tid < off) { si[tid] += si[tid + off]; sc[tid] += sc[tid + off]; }
        __syncthreads();
    }

    if (tid == 0) {
        const float fi = (float)si[0];
        const float f1 = (float)(c1part[2 * b] + c1part[2 * b + 1]);
        const float f2 = (float)sc[0];
        const float un = f1 + f2 - fi;
        float jac, ratio;
        if (fi == 0.0f && un == 0.0f) {        // zero_union -> 1.0, 1.0
            jac = 1.0f; ratio = 1.0f;
        } else {
            jac   = fi / un;                              // un > 0 here
            ratio = (f1 > 0.0f) ? (fi / f1) : 0.0f;       // 0/0 -> nan_to_num -> 0
        }
        out[n * NB + b]             = jac;     // iou.reshape(-1)
        out[NAUX * NB + n * NB + b] = ratio;   // corr.reshape(-1)
    }
}

extern "C" void kernel_launch(void* const* d_in, const int* in_sizes, int n_in,
                              void* d_out, int out_size, void* d_ws, size_t ws_size,
                              hipStream_t stream) {
    const float* qs = (const float*)d_in[0];   // [64, 80, 640]
    const float* qa = (const float*)d_in[1];   // [32, 64, 80, 640]
    float* out = (float*)d_out;                // [4096] = iou ++ corr

    unsigned char* maskb = (unsigned char*)d_ws;                 // 819200 bytes
    unsigned int*  c1p   = (unsigned int*)(maskb + NGRP);        // 128 words

    strain_mask_kernel<<<128, 256, 0, stream>>>(qs, maskb, c1p);
    aux_stats_kernel<<<NAUX * NB, 256, 0, stream>>>(qa, maskb, c1p, out);
}

// Round 3
// 104.147 us; speedup vs baseline: 1.7775x; 1.0596x over previous
//
#include <hip/hip_runtime.h>
#include <math.h>

// Problem geometry (fixed by the reference's setup_inputs)
#define NAUX 32
#define NB   64
#define NF   80
#define NT   640
#define PERB (NF * NT)          // 51200 elements per batch
#define NTOT (NB * PERB)        // 3276800 elements per channel
#define NGRP (NTOT / 4)         // 819200 4-element groups -> mask bytes
#define THR  20.0f

// ---------------------------------------------------------------------------
// Strict-local-max predicate over the FULL flattened [B,F,T] channel (peaks
// cross batch boundaries; only channel-flat 0 and NTOT-1 excluded).
// clip(min=0) is a no-op given the >=20 requirement.
// Mask layout: byte g holds the 4-bit predicate nibble for elements 4g..4g+3.
// ---------------------------------------------------------------------------

// Kernel A: 128 blocks = 2 per batch. float4 loads; neighbor exchange via
// wave shuffles (DS pipe) instead of lane-strided scalar gathers (L1 pipe).
__global__ __launch_bounds__(256) void strain_mask_kernel(
    const float* __restrict__ qs,
    unsigned char* __restrict__ maskb,
    unsigned int* __restrict__ c1part)
{
    const int b    = blockIdx.x >> 1;
    const int half = blockIdx.x & 1;
    const int tid  = threadIdx.x;
    const int lane = tid & 63;
    const int base0 = b * PERB + half * (PERB / 2);
    unsigned int cnt = 0;

    for (int it = 0; it < (PERB / 2) / (256 * 4); ++it) {   // 25 iterations
        const int e = base0 + (it * 256 + tid) * 4;         // channel-flat, %4==0
        const float4 v = *reinterpret_cast<const float4*>(qs + e);
        float xm = __shfl_up(v.w, 1);
        float xp = __shfl_down(v.x, 1);
        if (lane == 0)  xm = (e == 0)        ? INFINITY : qs[e - 1];
        if (lane == 63) xp = (e == NTOT - 4) ? INFINITY : qs[e + 4];

        unsigned int pb = 0;
        pb |= ((v.x >= THR) && (v.x > xm)  && (v.x > v.y)) ? 1u : 0u;
        pb |= ((v.y >= THR) && (v.y > v.x) && (v.y > v.z)) ? 2u : 0u;
        pb |= ((v.z >= THR) && (v.z > v.y) && (v.z > v.w)) ? 4u : 0u;
        pb |= ((v.w >= THR) && (v.w > v.z) && (v.w > xp))  ? 8u : 0u;

        maskb[e >> 2] = (unsigned char)pb;                  // coalesced bytes
        cnt += __popc(pb);
    }

    __shared__ unsigned int s[256];
    s[tid] = cnt;
    __syncthreads();
    for (int off = 128; off > 0; off >>= 1) {
        if (tid < off) s[tid] += s[tid + off];
        __syncthreads();
    }
    if (tid == 0) c1part[blockIdx.x] = s[0];
}

// Kernel B: one block per (aux channel n, batch b). 10 outer x 5 inner,
// all 5 float4 + 5 mask-byte loads hoisted and issued before compute so
// each wave keeps 5 x 16B loads in flight (MLP), instead of 1.
#define UNR 5
__global__ __launch_bounds__(256) void aux_stats_kernel(
    const float* __restrict__ qa,
    const unsigned char* __restrict__ maskb,
    const unsigned int* __restrict__ c1part,
    float* __restrict__ out)
{
    const int n    = blockIdx.x >> 6;   // / NB
    const int b    = blockIdx.x & 63;   // % NB
    const int tid  = threadIdx.x;
    const int lane = tid & 63;
    const float* __restrict__ pn = qa + (size_t)n * NTOT;

    unsigned int inter = 0, c2 = 0;

    for (int ot = 0; ot < PERB / (256 * 4 * UNR); ++ot) {   // 10 outer iters
        float4       v[UNR];
        unsigned int sm[UNR];
        const int ebase = b * PERB + (ot * UNR * 256 + tid) * 4;

        #pragma unroll
        for (int k = 0; k < UNR; ++k)
            v[k] = *reinterpret_cast<const float4*>(pn + ebase + k * 1024);
        #pragma unroll
        for (int k = 0; k < UNR; ++k)
            sm[k] = maskb[(ebase + k * 1024) >> 2];

        #pragma unroll
        for (int k = 0; k < UNR; ++k) {
            const int e = ebase + k * 1024;
            float xm = __shfl_up(v[k].w, 1);
            float xp = __shfl_down(v[k].x, 1);
            if (lane == 0)  xm = (e == 0)        ? INFINITY : pn[e - 1];
            if (lane == 63) xp = (e == NTOT - 4) ? INFINITY : pn[e + 4];

            unsigned int pb = 0;
            pb |= ((v[k].x >= THR) && (v[k].x > xm)     && (v[k].x > v[k].y)) ? 1u : 0u;
            pb |= ((v[k].y >= THR) && (v[k].y > v[k].x) && (v[k].y > v[k].z)) ? 2u : 0u;
            pb |= ((v[k].z >= THR) && (v[k].z > v[k].y) && (v[k].z > v[k].w)) ? 4u : 0u;
            pb |= ((v[k].w >= THR) && (v[k].w > v[k].z) && (v[k].w > xp))     ? 8u : 0u;

            c2    += __popc(pb);
            inter += __popc(pb & sm[k]);
        }
    }

    __shared__ unsigned int si[256];
    __shared__ unsigned int sc[256];
    si[tid] = inter; sc[tid] = c2;
    __syncthreads();
    for (int off = 128; off > 0; off >>= 1) {
        if (tid < off) { si[tid] += si[tid + off]; sc[tid] += sc[tid + off]; }
        __syncthreads();
    }

    if (tid == 0) {
        const float fi = (float)si[0];
        const float f1 = (float)(c1part[2 * b] + c1part[2 * b + 1]);
        const float f2 = (float)sc[0];
        const float un = f1 + f2 - fi;
        float jac, ratio;
        if (fi == 0.0f && un == 0.0f) {        // zero_union -> 1.0, 1.0
            jac = 1.0f; ratio = 1.0f;
        } else {
            jac   = fi / un;                              // un > 0 here
            ratio = (f1 > 0.0f) ? (fi / f1) : 0.0f;       // 0/0 -> nan_to_num -> 0
        }
        out[n * NB + b]             = jac;     // iou.reshape(-1)
        out[NAUX * NB + n * NB + b] = ratio;   // corr.reshape(-1)
    }
}

extern "C" void kernel_launch(void* const* d_in, const int* in_sizes, int n_in,
                              void* d_out, int out_size, void* d_ws, size_t ws_size,
                              hipStream_t stream) {
    const float* qs = (const float*)d_in[0];   // [64, 80, 640]
    const float* qa = (const float*)d_in[1];   // [32, 64, 80, 640]
    float* out = (float*)d_out;                // [4096] = iou ++ corr

    unsigned char* maskb = (unsigned char*)d_ws;                 // 819200 bytes
    unsigned int*  c1p   = (unsigned int*)(maskb + NGRP);        // 128 words

    strain_mask_kernel<<<128, 256, 0, stream>>>(qs, maskb, c1p);
    aux_stats_kernel<<<NAUX * NB, 256, 0, stream>>>(qa, maskb, c1p, out);
}

// Round 4
// 90.291 us; speedup vs baseline: 2.0502x; 1.1535x over previous
//
#include <hip/hip_runtime.h>
#include <math.h>

// Problem geometry (fixed by the reference's setup_inputs)
#define NAUX 32
#define NB   64
#define NF   80
#define NT   640
#define PERB (NF * NT)          // 51200 elements per batch
#define NTOT (NB * PERB)        // 3276800 elements per channel
#define NGRP (NTOT / 4)         // 819200 4-element groups -> mask bytes
#define THR  20.0f
#define ASEG 10                 // segments per batch in kernel A
#define AUNR 5                  // float4 iters per thread in kernel A (fully unrolled)
#define UNR  10                 // float4 loads in flight per thread in kernel B

// ---------------------------------------------------------------------------
// Strict-local-max predicate over the FULL flattened [B,F,T] channel (peaks
// cross batch boundaries; only channel-flat 0 and NTOT-1 excluded).
// clip(min=0) is a no-op given the >=20 requirement.
// Mask layout: byte g holds the 4-bit predicate nibble for elements 4g..4g+3.
// ---------------------------------------------------------------------------

// Kernel A: 640 blocks = 10 per batch; 5 float4 loads fully unrolled so the
// whole strain read is BW-bound, not latency-bound (Little's law: need ~6 MB
// in flight chip-wide; 2560 waves x 5KB = 12.8 MB).
__global__ __launch_bounds__(256) void strain_mask_kernel(
    const float* __restrict__ qs,
    unsigned char* __restrict__ maskb,
    unsigned int* __restrict__ c1part)
{
    const int b    = blockIdx.x / ASEG;
    const int seg  = blockIdx.x % ASEG;
    const int tid  = threadIdx.x;
    const int lane = tid & 63;
    const int base0 = b * PERB + seg * (PERB / ASEG);   // 5120-elem segment

    float4 v[AUNR];
    #pragma unroll
    for (int k = 0; k < AUNR; ++k)
        v[k] = *reinterpret_cast<const float4*>(qs + base0 + (k * 256 + tid) * 4);

    unsigned int cnt = 0;
    #pragma unroll
    for (int k = 0; k < AUNR; ++k) {
        const int e = base0 + (k * 256 + tid) * 4;
        float xm = __shfl_up(v[k].w, 1);
        float xp = __shfl_down(v[k].x, 1);
        if (lane == 0)  xm = (e == 0)        ? INFINITY : qs[e - 1];
        if (lane == 63) xp = (e == NTOT - 4) ? INFINITY : qs[e + 4];

        unsigned int pb = 0;
        pb |= ((v[k].x >= THR) && (v[k].x > xm)     && (v[k].x > v[k].y)) ? 1u : 0u;
        pb |= ((v[k].y >= THR) && (v[k].y > v[k].x) && (v[k].y > v[k].z)) ? 2u : 0u;
        pb |= ((v[k].z >= THR) && (v[k].z > v[k].y) && (v[k].z > v[k].w)) ? 4u : 0u;
        pb |= ((v[k].w >= THR) && (v[k].w > v[k].z) && (v[k].w > xp))     ? 8u : 0u;

        maskb[e >> 2] = (unsigned char)pb;                  // coalesced bytes
        cnt += __popc(pb);
    }

    __shared__ unsigned int s[256];
    s[tid] = cnt;
    __syncthreads();
    for (int off = 128; off > 0; off >>= 1) {
        if (tid < off) s[tid] += s[tid + off];
        __syncthreads();
    }
    if (tid == 0) c1part[blockIdx.x] = s[0];
}

// Kernel B: one block per (aux channel n, batch b). 5 outer x 10 inner;
// all 10 float4 + 10 mask-byte loads hoisted -> deep MLP, few waitcnt drains.
__global__ __launch_bounds__(256) void aux_stats_kernel(
    const float* __restrict__ qa,
    const unsigned char* __restrict__ maskb,
    const unsigned int* __restrict__ c1part,
    float* __restrict__ out)
{
    const int n    = blockIdx.x >> 6;   // / NB
    const int b    = blockIdx.x & 63;   // % NB
    const int tid  = threadIdx.x;
    const int lane = tid & 63;
    const float* __restrict__ pn = qa + (size_t)n * NTOT;

    unsigned int inter = 0, c2 = 0;

    for (int ot = 0; ot < PERB / (256 * 4 * UNR); ++ot) {   // 5 outer iters
        float4       v[UNR];
        unsigned int sm[UNR];
        const int ebase = b * PERB + (ot * UNR * 256 + tid) * 4;

        #pragma unroll
        for (int k = 0; k < UNR; ++k)
            v[k] = *reinterpret_cast<const float4*>(pn + ebase + k * 1024);
        #pragma unroll
        for (int k = 0; k < UNR; ++k)
            sm[k] = maskb[(ebase + k * 1024) >> 2];

        #pragma unroll
        for (int k = 0; k < UNR; ++k) {
            const int e = ebase + k * 1024;
            float xm = __shfl_up(v[k].w, 1);
            float xp = __shfl_down(v[k].x, 1);
            if (lane == 0)  xm = (e == 0)        ? INFINITY : pn[e - 1];
            if (lane == 63) xp = (e == NTOT - 4) ? INFINITY : pn[e + 4];

            unsigned int pb = 0;
            pb |= ((v[k].x >= THR) && (v[k].x > xm)     && (v[k].x > v[k].y)) ? 1u : 0u;
            pb |= ((v[k].y >= THR) && (v[k].y > v[k].x) && (v[k].y > v[k].z)) ? 2u : 0u;
            pb |= ((v[k].z >= THR) && (v[k].z > v[k].y) && (v[k].z > v[k].w)) ? 4u : 0u;
            pb |= ((v[k].w >= THR) && (v[k].w > v[k].z) && (v[k].w > xp))     ? 8u : 0u;

            c2    += __popc(pb);
            inter += __popc(pb & sm[k]);
        }
    }

    __shared__ unsigned int si[256];
    __shared__ unsigned int sc[256];
    si[tid] = inter; sc[tid] = c2;
    __syncthreads();
    for (int off = 128; off > 0; off >>= 1) {
        if (tid < off) { si[tid] += si[tid + off]; sc[tid] += sc[tid + off]; }
        __syncthreads();
    }

    if (tid == 0) {
        unsigned int c1 = 0;
        #pragma unroll
        for (int s2 = 0; s2 < ASEG; ++s2) c1 += c1part[b * ASEG + s2];
        const float fi = (float)si[0];
        const float f1 = (float)c1;
        const float f2 = (float)sc[0];
        const float un = f1 + f2 - fi;
        float jac, ratio;
        if (fi == 0.0f && un == 0.0f) {        // zero_union -> 1.0, 1.0
            jac = 1.0f; ratio = 1.0f;
        } else {
            jac   = fi / un;                              // un > 0 here
            ratio = (f1 > 0.0f) ? (fi / f1) : 0.0f;       // 0/0 -> nan_to_num -> 0
        }
        out[n * NB + b]             = jac;     // iou.reshape(-1)
        out[NAUX * NB + n * NB + b] = ratio;   // corr.reshape(-1)
    }
}

extern "C" void kernel_launch(void* const* d_in, const int* in_sizes, int n_in,
                              void* d_out, int out_size, void* d_ws, size_t ws_size,
                              hipStream_t stream) {
    const float* qs = (const float*)d_in[0];   // [64, 80, 640]
    const float* qa = (const float*)d_in[1];   // [32, 64, 80, 640]
    float* out = (float*)d_out;                // [4096] = iou ++ corr

    unsigned char* maskb = (unsigned char*)d_ws;                 // 819200 bytes
    unsigned int*  c1p   = (unsigned int*)(maskb + NGRP);        // 640 words

    strain_mask_kernel<<<NB * ASEG, 256, 0, stream>>>(qs, maskb, c1p);
    aux_stats_kernel<<<NAUX * NB, 256, 0, stream>>>(qa, maskb, c1p, out);
}

// Round 5
// 82.666 us; speedup vs baseline: 2.2393x; 1.0922x over previous
//
#include <hip/hip_runtime.h>
#include <math.h>

// Problem geometry (fixed by the reference's setup_inputs)
#define NAUX 32
#define NB   64
#define NF   80
#define NT   640
#define PERB (NF * NT)          // 51200 elements per batch
#define NTOT (NB * PERB)        // 3276800 elements per channel
#define NGRP (NTOT / 4)         // 819200 4-element groups -> mask bytes
#define THR  20.0f
#define UNR  5                  // k-chunks per wave-run (1280 elems = 5 x 256)
#define WRUN (UNR * 256)        // elements per wave run
#define ASEG 10                 // A: blocks per batch (5120 elems each)

// ---------------------------------------------------------------------------
// Strict-local-max predicate over the FULL flattened [B,F,T] channel (peaks
// cross batch boundaries; only channel-flat 0 and NTOT-1 excluded).
// clip(min=0) is a no-op given the >=20 requirement.
// Mask layout: byte g holds the 4-bit predicate nibble for elements 4g..4g+3.
//
// Wave-private runs: each wave covers 1280 contiguous elements (5 float4
// chunks, lane-contiguous per chunk). ALL neighbor exchange is intra-wave
// (shuffles + k+-1 broadcasts) except the run's two boundary elements,
// loaded once per run WITH the main burst -> one counted vmcnt drain per
// outer iter, no per-k vmcnt(0) poison, no barriers in the hot loop.
// ---------------------------------------------------------------------------

// Per-wave run processing: returns {c2, inter-with-mask} or just writes mask.
// (Shared predicate logic kept inline in both kernels for scheduling freedom.)

// Kernel A: 640 blocks; block covers 5120 elements = 4 wave-runs.
__global__ __launch_bounds__(256) void strain_mask_kernel(
    const float* __restrict__ qs,
    unsigned char* __restrict__ maskb,
    unsigned int* __restrict__ c1part)
{
    const int tid  = threadIdx.x;
    const int lane = tid & 63;
    const int w    = tid >> 6;
    const int base = blockIdx.x * (4 * WRUN) + w * WRUN + lane * 4;

    float4 v[UNR];
    #pragma unroll
    for (int k = 0; k < UNR; ++k)
        v[k] = *reinterpret_cast<const float4*>(qs + base + k * 256);

    float xmE = INFINITY, xpE = INFINITY;
    if (lane == 0)  { const int g = base - 1;                  if (g >= 0)   xmE = qs[g]; }
    if (lane == 63) { const int g = base + (UNR - 1) * 256 + 4; if (g < NTOT) xpE = qs[g]; }

    unsigned int cnt = 0;
    #pragma unroll
    for (int k = 0; k < UNR; ++k) {
        const float prevw = __shfl(v[k > 0 ? k - 1 : 0].w, 63);       // full-wave bcast
        const float nextx = __shfl(v[k < UNR - 1 ? k + 1 : UNR - 1].x, 0);
        float xm = __shfl_up(v[k].w, 1);
        float xp = __shfl_down(v[k].x, 1);
        xm = (lane == 0)  ? ((k > 0)       ? prevw : xmE) : xm;
        xp = (lane == 63) ? ((k < UNR - 1) ? nextx : xpE) : xp;

        unsigned int pb = 0;
        pb |= ((v[k].x >= THR) && (v[k].x > xm)     && (v[k].x > v[k].y)) ? 1u : 0u;
        pb |= ((v[k].y >= THR) && (v[k].y > v[k].x) && (v[k].y > v[k].z)) ? 2u : 0u;
        pb |= ((v[k].z >= THR) && (v[k].z > v[k].y) && (v[k].z > v[k].w)) ? 4u : 0u;
        pb |= ((v[k].w >= THR) && (v[k].w > v[k].z) && (v[k].w > xp))     ? 8u : 0u;

        maskb[(base + k * 256) >> 2] = (unsigned char)pb;   // coalesced bytes
        cnt += __popc(pb);
    }

    __shared__ unsigned int s[256];
    s[tid] = cnt;
    __syncthreads();
    for (int off = 128; off > 0; off >>= 1) {
        if (tid < off) s[tid] += s[tid + off];
        __syncthreads();
    }
    if (tid == 0) c1part[blockIdx.x] = s[0];
}

// Kernel B: one block per (aux channel n, batch b); 10 outer iters, each
// wave sweeping a private 1280-element run. No barriers in the loop.
__global__ __launch_bounds__(256) void aux_stats_kernel(
    const float* __restrict__ qa,
    const unsigned char* __restrict__ maskb,
    const unsigned int* __restrict__ c1part,
    float* __restrict__ out)
{
    const int n    = blockIdx.x >> 6;   // / NB
    const int b    = blockIdx.x & 63;   // % NB
    const int tid  = threadIdx.x;
    const int lane = tid & 63;
    const int w    = tid >> 6;
    const float* __restrict__ pn = qa + (size_t)n * NTOT;

    unsigned int inter = 0, c2 = 0;
    const int wbase0 = b * PERB + w * WRUN + lane * 4;

    for (int ot = 0; ot < PERB / (4 * WRUN); ++ot) {        // 10 outer iters
        const int base = wbase0 + ot * (4 * WRUN);

        float4       v[UNR];
        unsigned int sm[UNR];
        #pragma unroll
        for (int k = 0; k < UNR; ++k)
            v[k] = *reinterpret_cast<const float4*>(pn + base + k * 256);

        float xmE = INFINITY, xpE = INFINITY;
        if (lane == 0)  { const int g = base - 1;                   if (g >= 0)   xmE = pn[g]; }
        if (lane == 63) { const int g = base + (UNR - 1) * 256 + 4; if (g < NTOT) xpE = pn[g]; }

        #pragma unroll
        for (int k = 0; k < UNR; ++k)
            sm[k] = maskb[(base + k * 256) >> 2];

        #pragma unroll
        for (int k = 0; k < UNR; ++k) {
            const float prevw = __shfl(v[k > 0 ? k - 1 : 0].w, 63);
            const float nextx = __shfl(v[k < UNR - 1 ? k + 1 : UNR - 1].x, 0);
            float xm = __shfl_up(v[k].w, 1);
            float xp = __shfl_down(v[k].x, 1);
            xm = (lane == 0)  ? ((k > 0)       ? prevw : xmE) : xm;
            xp = (lane == 63) ? ((k < UNR - 1) ? nextx : xpE) : xp;

            unsigned int pb = 0;
            pb |= ((v[k].x >= THR) && (v[k].x > xm)     && (v[k].x > v[k].y)) ? 1u : 0u;
            pb |= ((v[k].y >= THR) && (v[k].y > v[k].x) && (v[k].y > v[k].z)) ? 2u : 0u;
            pb |= ((v[k].z >= THR) && (v[k].z > v[k].y) && (v[k].z > v[k].w)) ? 4u : 0u;
            pb |= ((v[k].w >= THR) && (v[k].w > v[k].z) && (v[k].w > xp))     ? 8u : 0u;

            c2    += __popc(pb);
            inter += __popc(pb & sm[k]);
        }
    }

    __shared__ unsigned int si[256];
    __shared__ unsigned int sc[256];
    si[tid] = inter; sc[tid] = c2;
    __syncthreads();
    for (int off = 128; off > 0; off >>= 1) {
        if (tid < off) { si[tid] += si[tid + off]; sc[tid] += sc[tid + off]; }
        __syncthreads();
    }

    if (tid == 0) {
        unsigned int c1 = 0;
        #pragma unroll
        for (int s2 = 0; s2 < ASEG; ++s2) c1 += c1part[b * ASEG + s2];
        const float fi = (float)si[0];
        const float f1 = (float)c1;
        const float f2 = (float)sc[0];
        const float un = f1 + f2 - fi;
        float jac, ratio;
        if (fi == 0.0f && un == 0.0f) {        // zero_union -> 1.0, 1.0
            jac = 1.0f; ratio = 1.0f;
        } else {
            jac   = fi / un;                              // un > 0 here
            ratio = (f1 > 0.0f) ? (fi / f1) : 0.0f;       // 0/0 -> nan_to_num -> 0
        }
        out[n * NB + b]             = jac;     // iou.reshape(-1)
        out[NAUX * NB + n * NB + b] = ratio;   // corr.reshape(-1)
    }
}

extern "C" void kernel_launch(void* const* d_in, const int* in_sizes, int n_in,
                              void* d_out, int out_size, void* d_ws, size_t ws_size,
                              hipStream_t stream) {
    const float* qs = (const float*)d_in[0];   // [64, 80, 640]
    const float* qa = (const float*)d_in[1];   // [32, 64, 80, 640]
    float* out = (float*)d_out;                // [4096] = iou ++ corr

    unsigned char* maskb = (unsigned char*)d_ws;                 // 819200 bytes
    unsigned int*  c1p   = (unsigned int*)(maskb + NGRP);        // 640 words

    strain_mask_kernel<<<NB * ASEG, 256, 0, stream>>>(qs, maskb, c1p);
    aux_stats_kernel<<<NAUX * NB, 256, 0, stream>>>(qa, maskb, c1p, out);
}